// Round 20
// baseline (368.276 us; speedup 1.0000x reference)
//
#include <hip/hip_runtime.h>
#include <hip/hip_bf16.h>
#include <math.h>

// Problem constants
#define BQ 8
#define C1N 512
#define N1 784          // 28*28
#define C2N 1024
#define M2 196          // 14*14
#define NROWS 6272      // 8*784 = 49*128
#define MEMN 20000
#define MEMNP 20096     // 157*128
#define DIMK 1024
#define NKB 32          // K blocks of 32
#define AKB 4096        // A bytes per K-block per 128-row tile
#define BKB 4096        // B bytes per K-block per 128-row tile
#define OUTHW 50176     // 224*224
#define NTILEA 49
#define NTILEB 157
#define NWG (NTILEB * NTILEA)   // 7693

typedef unsigned char u8;
typedef long long i64;
typedef __attribute__((ext_vector_type(2))) long long ll2;
typedef __attribute__((ext_vector_type(16))) float f32x16;

// ---- order-preserving float <-> uint for atomicMin ----
static __device__ __forceinline__ unsigned int f2ord(float f) {
  unsigned int b = __float_as_uint(f);
  return (b & 0x80000000u) ? ~b : (b | 0x80000000u);
}
static __device__ __forceinline__ float ord2f(unsigned int u) {
  unsigned int b = (u & 0x80000000u) ? (u ^ 0x80000000u) : ~u;
  return __uint_as_float(b);
}

// ---- fp8 e4m3 (OCP) pack/unpack via HW converts ----
static __device__ __forceinline__ int pack4_fp8(float a, float b, float c, float d) {
  int lo = __builtin_amdgcn_cvt_pk_fp8_f32(a, b, 0, false);
  return __builtin_amdgcn_cvt_pk_fp8_f32(c, d, lo, true);
}
static __device__ __forceinline__ float sumsq4_fp8(int w) {
  float f0 = __builtin_amdgcn_cvt_f32_fp8(w, 0);
  float f1 = __builtin_amdgcn_cvt_f32_fp8(w, 1);
  float f2 = __builtin_amdgcn_cvt_f32_fp8(w, 2);
  float f3 = __builtin_amdgcn_cvt_f32_fp8(w, 3);
  return f0 * f0 + f1 * f1 + f2 * f2 + f3 * f3;
}

// ---- async global->LDS (16B per lane; LDS dest = wave-uniform base + lane*16) ----
static __device__ __forceinline__ void gload16(const void* g, void* l) {
  __builtin_amdgcn_global_load_lds((const __attribute__((address_space(1))) void*)g,
                                   (__attribute__((address_space(3))) void*)l, 16, 0, 0);
}

// ---- A tiled layout for 32x32x16 fragments (per-lane-contiguous 32B) ----
// [tile][kb=32][wrb=2][kg=2][r=32][mi=2][kh=2][e=8] bytes.
// row = wrb*64 + mi*32 + r ; k = kb*32 + kh*16 + kg*8 + e.
static __device__ __forceinline__ size_t tiled_a_idx(int grow, int k) {
  int tile = grow >> 7, rowt = grow & 127;
  int wrb = rowt >> 6, mi = (rowt >> 5) & 1, r = rowt & 31;
  int kb = k >> 5, kh = (k >> 4) & 1, kg = (k >> 3) & 1, e = k & 7;
  return ((((size_t)(tile * NKB + kb) * 2 + wrb) * 2 + kg) * 32 + r) * 32 + mi * 16 + kh * 8 + e;
}

// ---- scrambled patchify flat-index decode ----
// Reference's patchify flattens per-batch in (kj, w, c, ki, h) row-major order:
//   L = (((kj*W + w)*C + c)*3 + ki)*H + h ; value = x[b, c, h+ki-1, w+kj-1] (0 if OOB)
static __device__ __forceinline__ float f1val(const float* __restrict__ x, int b, unsigned L) {
  unsigned h = L % 28u; unsigned t = L / 28u;
  unsigned ki = t % 3u; t /= 3u;
  unsigned c = t % 512u; t /= 512u;
  unsigned w = t % 28u; unsigned kj = t / 28u;
  unsigned y = h + ki - 1u;   // wraps to huge if -1
  unsigned xx = w + kj - 1u;
  if (y >= 28u || xx >= 28u) return 0.f;
  return x[(((size_t)b * 512u + c) * 28u + y) * 28u + xx];
}
static __device__ __forceinline__ float f2val(const float* __restrict__ x, int b, unsigned L) {
  unsigned h = L % 14u; unsigned t = L / 14u;
  unsigned ki = t % 3u; t /= 3u;
  unsigned c = t % 1024u; t /= 1024u;
  unsigned w = t % 14u; unsigned kj = t / 14u;
  unsigned y = h + ki - 1u;
  unsigned xx = w + kj - 1u;
  if (y >= 14u || xx >= 14u) return 0.f;
  return x[(((size_t)b * 1024u + c) * 14u + y) * 14u + xx];
}

// feats[b,n,j<512] = (sum_{u=0..8} F1[9*(512n+j)+u] + F1[...+4]) / 10  -> fp8 A-tiled
// j FASTEST across lanes: a wave's gathers stay in a ~22 KB L1-resident window.
__global__ __launch_bounds__(256) void feat_a_fp8(const float* __restrict__ feat1,
                                                  u8* __restrict__ At) {
  int id = blockIdx.x * 256 + threadIdx.x;
  if (id >= BQ * N1 * 512) return;
  int j = id & 511; int t = id >> 9;
  int n = t % N1; int b = t / N1;
  unsigned L0 = 9u * (unsigned)(512 * n + j);
  float s = 0.f;
#pragma unroll
  for (int u = 0; u < 9; ++u) s += f1val(feat1, b, L0 + u);
  s += f1val(feat1, b, L0 + 4u);
  int p = __builtin_amdgcn_cvt_pk_fp8_f32(s * 0.1f, s * 0.1f, 0, false);
  At[tiled_a_idx(b * N1 + n, j)] = (u8)(p & 0xFF);
}

// H2all[b][n2][i] = (1/18) sum_{u<18} F2[18*(512*n2+i)+u]
__global__ __launch_bounds__(256) void feat_b_stage1(const float* __restrict__ feat2,
                                                     float* __restrict__ H2all) {
  int b = blockIdx.x / M2;
  int n2 = blockIdx.x % M2;
  for (int i = threadIdx.x; i < 512; i += 256) {
    unsigned L0 = 18u * (unsigned)(512 * n2 + i);
    float s = 0.f;
#pragma unroll
    for (int u = 0; u < 18; ++u) s += f2val(feat2, b, L0 + u);
    H2all[((size_t)b * M2 + n2) * 512 + i] = s * (1.0f / 18.0f);
  }
}

// bilinear 14x14 -> 28x28 over the n2 grid, write feats[b,n,512+i] -> fp8 A-tiled
__global__ __launch_bounds__(256) void feat_b_stage2_fp8(const float* __restrict__ H2all,
                                                         u8* __restrict__ At) {
  int id = blockIdx.x * 256 + threadIdx.x;
  if (id >= BQ * 64 * N1) return;
  int n = id % N1; int t = id / N1;
  int ic = t % 64; int b = t / 64;
  int y = n / 28, x = n % 28;
  float sy = 0.5f * (float)y - 0.25f;
  sy = fminf(fmaxf(sy, 0.f), 13.f);
  int y0 = (int)sy, y1 = min(y0 + 1, 13);
  float wy = sy - (float)y0;
  float sx = 0.5f * (float)x - 0.25f;
  sx = fminf(fmaxf(sx, 0.f), 13.f);
  int x0 = (int)sx, x1 = min(x0 + 1, 13);
  float wx = sx - (float)x0;
  float w00 = (1.f - wy) * (1.f - wx), w10 = wy * (1.f - wx);
  float w01 = (1.f - wy) * wx, w11 = wy * wx;
  const float* h00 = H2all + ((size_t)b * M2 + y0 * 14 + x0) * 512 + ic * 8;
  const float* h10 = H2all + ((size_t)b * M2 + y1 * 14 + x0) * 512 + ic * 8;
  const float* h01 = H2all + ((size_t)b * M2 + y0 * 14 + x1) * 512 + ic * 8;
  const float* h11 = H2all + ((size_t)b * M2 + y1 * 14 + x1) * 512 + ic * 8;
  float v[8];
#pragma unroll
  for (int e = 0; e < 8; ++e)
    v[e] = w00 * h00[e] + w10 * h10[e] + w01 * h01[e] + w11 * h11[e];
  int w0 = pack4_fp8(v[0], v[1], v[2], v[3]);
  int w1 = pack4_fp8(v[4], v[5], v[6], v[7]);
  *(int2*)&At[tiled_a_idx(b * N1 + n, 512 + ic * 8)] = make_int2(w0, w1);
}

// memory fp32 -> fp8 B-tiled [tile][kb=32][c=4][row=128][e=8]; rows [MEMN,MEMNP)=0.
__global__ __launch_bounds__(256) void memconv_fp8(const float* __restrict__ mem,
                                                   u8* __restrict__ Bt) {
  int gid = blockIdx.x * 256 + threadIdx.x;
  if (gid >= NTILEB * NKB * 512) return;
  int tile = gid >> 14;            // 32*512 units per tile
  int within = gid & 16383;
  int kb = within >> 9;
  int u = within & 511;
  int c = u >> 7, row = u & 127;
  int n = tile * 128 + row;
  int k0 = kb * 32 + c * 8;
  int w0 = 0, w1 = 0;
  if (n < MEMN) {
    const float* src = mem + (size_t)n * DIMK + k0;
    float4 a = *(const float4*)src;
    float4 b = *(const float4*)(src + 4);
    w0 = pack4_fp8(a.x, a.y, a.z, a.w);
    w1 = pack4_fp8(b.x, b.y, b.z, b.w);
  }
  *(int2*)&Bt[(size_t)gid * 8] = make_int2(w0, w1);
}

// mnorm from fp8 Bt (identical quantized values, 20 MB instead of 80 MB).
__global__ __launch_bounds__(256) void mnorm_fp8(const u8* __restrict__ Bt,
                                                 float* __restrict__ mnorm) {
  __shared__ float part[2][128];
  int tile = blockIdx.x;
  int r = threadIdx.x & 127, hh = threadIdx.x >> 7;
  const u8* base = Bt + (size_t)tile * (NKB * BKB) + r * 8;
  float s = 0.f;
#pragma unroll 4
  for (int ch = hh * 64; ch < hh * 64 + 64; ++ch) {   // chunk = kb*4+c
    int2 d = *(const int2*)(base + (size_t)ch * 1024);
    s += sumsq4_fp8(d.x) + sumsq4_fp8(d.y);
  }
  part[hh][r] = s;
  __syncthreads();
  if (threadIdx.x < 128) {
    int n = tile * 128 + threadIdx.x;
    if (n < MEMN) mnorm[n] = part[0][threadIdx.x] + part[1][threadIdx.x];
  }
}

// ---- fp8 MFMA distance GEMM + row-min (32x32x16 shape) ----
// 128x128 tile, BK=32, 4 waves (2x2, per-wave 64x64 = 2x2 of 32x32). A: global->reg
// direct (32B contiguous/lane/K-tile = 2 dwordx4). B: LDS, 4 slots x 4KB staged 3
// ahead. vmcnt ledger identical to round-17: per iter issue [A2(k+1), B1(k+3)];
// need B(k+1) before SBAR(k) -> newer = 6 -> vmcnt(6); tail 6/5/4.
// Per K-tile: 8 MFMA (vs 16 at 16x16x32) at same A/B traffic -> less issue pressure.
// Fragment k-convention (A and B identical): k = kh*16 + kg*8 + e, kg = lane>>5,
// row/col = lane&31. C/D: col=lane&31, row=(reg&3)+8*(reg>>2)+4*kg (guide-verified).
// NOTE: (256,4) is the occupancy ceiling — unified demand ~60 VGPR + 64 AGPR (acc);
// an 8-wave bound spills the accumulator (round-18: 17x slowdown). Do not raise.
__global__ __launch_bounds__(256, 4) void dist_min_mfma(const u8* __restrict__ At,
                                                        const u8* __restrict__ Bt,
                                                        const float* __restrict__ mnorm,
                                                        unsigned int* __restrict__ minu) {
  __shared__ __align__(16) u8 LBs[4][4096];
  const int t = threadIdx.x;
  const int wave = t >> 6, lane = t & 63;

  // bijective XCD chunking (m204): q=961, r=5
  int lid = blockIdx.x;
  const int q = NWG / 8, r = NWG % 8;
  int xcd = lid & 7, pos = lid >> 3;
  int wgid = (xcd < r ? xcd * (q + 1) : r * (q + 1) + (xcd - r) * q) + pos;
  // supertile: 7 row-tiles per group (49 = 7*7), rows fastest within a column
  int g = wgid / (NTILEB * 7), rem = wgid % (NTILEB * 7);
  int bx = rem / 7;            // col tile 0..156
  int by = g * 7 + rem % 7;    // row tile 0..48
  const int row0 = by * 128, col0 = bx * 128;

  f32x16 acc[2][2];
#pragma unroll
  for (int i = 0; i < 2; ++i)
#pragma unroll
    for (int j = 0; j < 2; ++j) acc[i][j] = (f32x16)0.0f;

  const int wrb = wave >> 1;             // A row-block (64 rows)
  const int wr = wrb * 64, wc = (wave & 1) * 64;
  const int kg = lane >> 5, r32 = lane & 31;
  // B LDS byte offset: c = kh*2+kg ; addr = ((kh*2+kg)*128 + wc+ni*32+r32)*8
  const int boff = kg * 1024 + (wc + r32) * 8;   // + kh*2048 + ni*256

  // per-lane A base: 32B fragment (mi,kh,e) at ((wrb*2+kg)*32+r32)*32, +AKB per kb
  const u8* aP = At + (size_t)by * (NKB * AKB) + ((wrb * 2 + kg) * 32 + r32) * 32;
  const u8* bG = Bt + (size_t)bx * (NKB * BKB) + t * 16;

  ll2 ar0[2], ar1[2];

#define LOAD_A(P, kb)                                        \
  do {                                                       \
    const u8* p_ = aP + (size_t)(kb) * AKB;                  \
    ar##P[0] = *(const ll2*)p_;                              \
    ar##P[1] = *(const ll2*)(p_ + 16);                       \
  } while (0)

#define STAGE_B(S, kb) gload16(bG + (size_t)(kb) * BKB, &LBs[S][wave * 1024])

#define SBAR __builtin_amdgcn_s_barrier()
#define VMW(n) asm volatile("s_waitcnt vmcnt(" #n ")" ::: "memory")

// ar{P}[mi].x = (mi,kh0) fragment, .y = (mi,kh1)
#define COMPUTE(S, P)                                                                        \
  do {                                                                                       \
    i64 b00 = *(const i64*)&LBs[S][boff];                                                    \
    i64 b01 = *(const i64*)&LBs[S][boff + 256];                                              \
    i64 b10 = *(const i64*)&LBs[S][boff + 2048];                                             \
    i64 b11 = *(const i64*)&LBs[S][boff + 2304];                                             \
    __builtin_amdgcn_s_setprio(1);                                                           \
    acc[0][0] = __builtin_amdgcn_mfma_f32_32x32x16_fp8_fp8(ar##P[0].x, b00, acc[0][0], 0, 0, 0); \
    acc[1][0] = __builtin_amdgcn_mfma_f32_32x32x16_fp8_fp8(ar##P[1].x, b00, acc[1][0], 0, 0, 0); \
    acc[0][1] = __builtin_amdgcn_mfma_f32_32x32x16_fp8_fp8(ar##P[0].x, b01, acc[0][1], 0, 0, 0); \
    acc[1][1] = __builtin_amdgcn_mfma_f32_32x32x16_fp8_fp8(ar##P[1].x, b01, acc[1][1], 0, 0, 0); \
    acc[0][0] = __builtin_amdgcn_mfma_f32_32x32x16_fp8_fp8(ar##P[0].y, b10, acc[0][0], 0, 0, 0); \
    acc[1][0] = __builtin_amdgcn_mfma_f32_32x32x16_fp8_fp8(ar##P[1].y, b10, acc[1][0], 0, 0, 0); \
    acc[0][1] = __builtin_amdgcn_mfma_f32_32x32x16_fp8_fp8(ar##P[0].y, b11, acc[0][1], 0, 0, 0); \
    acc[1][1] = __builtin_amdgcn_mfma_f32_32x32x16_fp8_fp8(ar##P[1].y, b11, acc[1][1], 0, 0, 0); \
    __builtin_amdgcn_s_setprio(0);                                                           \
  } while (0)

  // one K-tile: compute k (slot S, A-parity P), load A(kA), stage B(kS) into (S+3)&3
#define ITER(S, P, PN, kA, kS)       \
  do {                               \
    LOAD_A(PN, kA);                  \
    STAGE_B((S + 3) & 3, kS);        \
    COMPUTE(S, P);                   \
    VMW(6);                          \
    SBAR;                            \
  } while (0)

  // prologue: A(0) -> ar0; B(0..2) -> slots 0..2
  LOAD_A(0, 0);
  STAGE_B(0, 0);
  STAGE_B(1, 1);
  STAGE_B(2, 2);
  VMW(0);
  SBAR;

  // k = 0..27 (stages B(3..30), loads A(1..28))
#pragma unroll 1
  for (int i = 0; i < 7; ++i) {
    int k = i * 4;
    ITER(0, 0, 1, k + 1, k + 3);
    ITER(1, 1, 0, k + 2, k + 4);
    ITER(2, 0, 1, k + 3, k + 5);
    ITER(3, 1, 0, k + 4, k + 6);
  }
  // k=28: load A(29), stage B(31); need B(29): newer = 6
  LOAD_A(1, 29); STAGE_B(3, 31); COMPUTE(0, 0); VMW(6); SBAR;
  // k=29: load A(30); need B(30): newer = 5
  LOAD_A(0, 30); COMPUTE(1, 1); VMW(5); SBAR;
  // k=30: load A(31); need B(31): newer = 4
  LOAD_A(1, 31); COMPUTE(2, 0); VMW(4); SBAR;
  // k=31
  COMPUTE(3, 1);
#undef ITER
#undef COMPUTE
#undef LOAD_A
#undef STAGE_B
#undef VMW

  // epilogue: v = mnorm[col] - 2*dot ; per-lane min over ni, then min across the
  // 32-lane column group (offs 1..16 keep kg bit fixed); lane r32==0 writes.
  float cmn[2];
#pragma unroll
  for (int ni = 0; ni < 2; ++ni) {
    int gn = col0 + wc + ni * 32 + r32;
    cmn[ni] = (gn < MEMN) ? mnorm[gn] : INFINITY;
  }
#pragma unroll
  for (int mi = 0; mi < 2; ++mi) {
#pragma unroll
    for (int reg = 0; reg < 16; ++reg) {
      float v = fminf(fmaf(-2.f, acc[mi][0][reg], cmn[0]),
                      fmaf(-2.f, acc[mi][1][reg], cmn[1]));
#pragma unroll
      for (int off = 1; off < 32; off <<= 1)
        v = fminf(v, __shfl_xor(v, off, 64));
      if (r32 == 0) {
        int grow = row0 + wr + mi * 32 + (reg & 3) + 8 * (reg >> 2) + 4 * kg;
        atomicMin(&minu[grow], f2ord(v));
      }
    }
  }
}

// ================= epilogue kernels =================

// fused fnorm + scores: 1 wave per row
__global__ __launch_bounds__(256) void scores_fused(const u8* __restrict__ At,
                                                    const unsigned int* __restrict__ minu,
                                                    float* __restrict__ scores) {
  int row = blockIdx.x * 4 + (threadIdx.x >> 6);
  int lane = threadIdx.x & 63;
  float s = 0.f;
#pragma unroll
  for (int qq = 0; qq < 2; ++qq) {
    int2 d = *(const int2*)&At[tiled_a_idx(row, (lane + qq * 64) * 8)];
    s += sumsq4_fp8(d.x);
    s += sumsq4_fp8(d.y);
  }
#pragma unroll
  for (int off = 32; off; off >>= 1) s += __shfl_down(s, off, 64);
  if (lane == 0) scores[row] = sqrtf(fmaxf(s + ord2f(minu[row]), 0.f));
}

__global__ __launch_bounds__(256) void image_max_kernel(const float* __restrict__ scores,
                                                        float* __restrict__ out) {
  __shared__ float red[4];
  const int b = blockIdx.x;
  float m = -INFINITY;
  for (int n = threadIdx.x; n < N1; n += 256) m = fmaxf(m, scores[b * N1 + n]);
#pragma unroll
  for (int off = 32; off; off >>= 1) m = fmaxf(m, __shfl_down(m, off, 64));
  if ((threadIdx.x & 63) == 0) red[threadIdx.x >> 6] = m;
  __syncthreads();
  if (threadIdx.x == 0) out[b] = fmaxf(fmaxf(red[0], red[1]), fmaxf(red[2], red[3]));
}

__global__ __launch_bounds__(256) void upsample_kernel(const float* __restrict__ scores,
                                                       float* __restrict__ out) {
  int o = blockIdx.x * 256 + threadIdx.x;
  if (o >= BQ * OUTHW) return;
  int b = o / OUTHW, rem = o % OUTHW;
  int oy = rem / 224, ox = rem % 224;
  float sy = ((float)oy + 0.5f) * 0.125f - 0.5f;
  sy = fminf(fmaxf(sy, 0.f), 27.f);
  int y0 = (int)sy, y1 = min(y0 + 1, 27);
  float wy = sy - (float)y0;
  float sx = ((float)ox + 0.5f) * 0.125f - 0.5f;
  sx = fminf(fmaxf(sx, 0.f), 27.f);
  int x0 = (int)sx, x1 = min(x0 + 1, 27);
  float wx = sx - (float)x0;
  const float* s = scores + b * N1;
  float v0 = s[y0 * 28 + x0] * (1.f - wy) + s[y1 * 28 + x0] * wy;
  float v1 = s[y0 * 28 + x1] * (1.f - wy) + s[y1 * 28 + x1] * wy;
  out[BQ + o] = v0 * (1.f - wx) + v1 * wx;
}

extern "C" void kernel_launch(void* const* d_in, const int* in_sizes, int n_in,
                              void* d_out, int out_size, void* d_ws, size_t ws_size,
                              hipStream_t stream) {
  const float* feat1 = (const float*)d_in[0];
  const float* feat2 = (const float*)d_in[1];
  const float* memory = (const float*)d_in[2];
  float* out = (float*)d_out;

  char* ws = (char*)d_ws;
  size_t off = 0;
  auto wsalloc = [&](size_t bytes) {
    void* p = ws + off;
    off += (bytes + 255) & ~(size_t)255;
    return p;
  };

  u8* At = (u8*)wsalloc((size_t)NTILEA * NKB * AKB);   // 6.4 MB
  u8* Bt = (u8*)wsalloc((size_t)NTILEB * NKB * BKB);   // 20.6 MB
  float* mnorm = (float*)wsalloc((size_t)MEMN * 4);
  unsigned int* minu = (unsigned int*)wsalloc((size_t)NROWS * 4);
  float* scores = (float*)wsalloc((size_t)NROWS * 4);
  // H2all aliases Bt: stream order guarantees feat_b_stage1/2 finish before memconv
  // overwrites Bt (3.2 MB << Bt's 20.6 MB); mnorm reads Bt after memconv.
  float* H2all = (float*)Bt;

  feat_a_fp8<<<(BQ * N1 * 512) / 256, 256, 0, stream>>>(feat1, At);
  feat_b_stage1<<<BQ * M2, 256, 0, stream>>>(feat2, H2all);
  feat_b_stage2_fp8<<<(BQ * 64 * N1) / 256, 256, 0, stream>>>(H2all, At);
  memconv_fp8<<<(NTILEB * NKB * 512) / 256, 256, 0, stream>>>(memory, Bt);
  mnorm_fp8<<<NTILEB, 256, 0, stream>>>(Bt, mnorm);
  (void)hipMemsetAsync(minu, 0xFF, (size_t)NROWS * 4, stream);

  dist_min_mfma<<<NWG, 256, 0, stream>>>(At, Bt, mnorm, minu);

  scores_fused<<<NROWS / 4, 256, 0, stream>>>(At, minu, scores);
  image_max_kernel<<<BQ, 256, 0, stream>>>(scores, out);
  upsample_kernel<<<(BQ * OUTHW + 255) / 256, 256, 0, stream>>>(scores, out);
}

// Round 21
// 302.810 us; speedup vs baseline: 1.2162x; 1.2162x over previous
//
#include <hip/hip_runtime.h>
#include <hip/hip_bf16.h>
#include <math.h>

// Problem constants
#define BQ 8
#define C1N 512
#define N1 784          // 28*28
#define C2N 1024
#define M2 196          // 14*14
#define NROWS 6272      // 8*784 = 49*128
#define MEMN 20000
#define MEMNP 20096     // 157*128
#define DIMK 1024
#define NKB 32          // K blocks of 32
#define AKB 4096        // A bytes per K-block per 128-row tile
#define BKB 4096        // B bytes per K-block per 128-row tile
#define OUTHW 50176     // 224*224
#define NTILEA 49
#define NTILEB 157
#define NWG (NTILEB * NTILEA)   // 7693

typedef unsigned char u8;
typedef long long i64;
typedef __attribute__((ext_vector_type(2))) long long ll2;
typedef __attribute__((ext_vector_type(4))) float f32x4;

// ---- order-preserving float <-> uint for atomicMin ----
static __device__ __forceinline__ unsigned int f2ord(float f) {
  unsigned int b = __float_as_uint(f);
  return (b & 0x80000000u) ? ~b : (b | 0x80000000u);
}
static __device__ __forceinline__ float ord2f(unsigned int u) {
  unsigned int b = (u & 0x80000000u) ? (u ^ 0x80000000u) : ~u;
  return __uint_as_float(b);
}

// ---- fp8 e4m3 (OCP) pack/unpack via HW converts ----
static __device__ __forceinline__ int pack4_fp8(float a, float b, float c, float d) {
  int lo = __builtin_amdgcn_cvt_pk_fp8_f32(a, b, 0, false);
  return __builtin_amdgcn_cvt_pk_fp8_f32(c, d, lo, true);
}
static __device__ __forceinline__ float sumsq4_fp8(int w) {
  float f0 = __builtin_amdgcn_cvt_f32_fp8(w, 0);
  float f1 = __builtin_amdgcn_cvt_f32_fp8(w, 1);
  float f2 = __builtin_amdgcn_cvt_f32_fp8(w, 2);
  float f3 = __builtin_amdgcn_cvt_f32_fp8(w, 3);
  return f0 * f0 + f1 * f1 + f2 * f2 + f3 * f3;
}

// ---- async global->LDS (16B per lane; LDS dest = wave-uniform base + lane*16) ----
static __device__ __forceinline__ void gload16(const void* g, void* l) {
  __builtin_amdgcn_global_load_lds((const __attribute__((address_space(1))) void*)g,
                                   (__attribute__((address_space(3))) void*)l, 16, 0, 0);
}

// ---- A tiled layout (per-lane-contiguous 32B fragments) ----
// [tile][kb=32][half=2][fc=4][frow=16][mi=4][e=8] bytes.
// row = half*64 + mi*16 + frow ; k = kb*32 + fc*8 + e.
static __device__ __forceinline__ size_t tiled_a_idx(int grow, int k) {
  int tile = grow >> 7, row = grow & 127;
  int half = row >> 6, mi = (row >> 4) & 3, frow = row & 15;
  int kb = k >> 5, fc = (k >> 3) & 3, e = k & 7;
  return ((((((size_t)(tile * NKB + kb) * 2 + half) * 4 + fc) * 16 + frow) * 4 + mi) << 3) + e;
}

// ---- scrambled patchify flat-index decode ----
// Reference's patchify flattens per-batch in (kj, w, c, ki, h) row-major order:
//   L = (((kj*W + w)*C + c)*3 + ki)*H + h ; value = x[b, c, h+ki-1, w+kj-1] (0 if OOB)
static __device__ __forceinline__ float f1val(const float* __restrict__ x, int b, unsigned L) {
  unsigned h = L % 28u; unsigned t = L / 28u;
  unsigned ki = t % 3u; t /= 3u;
  unsigned c = t % 512u; t /= 512u;
  unsigned w = t % 28u; unsigned kj = t / 28u;
  unsigned y = h + ki - 1u;   // wraps to huge if -1
  unsigned xx = w + kj - 1u;
  if (y >= 28u || xx >= 28u) return 0.f;
  return x[(((size_t)b * 512u + c) * 28u + y) * 28u + xx];
}
static __device__ __forceinline__ float f2val(const float* __restrict__ x, int b, unsigned L) {
  unsigned h = L % 14u; unsigned t = L / 14u;
  unsigned ki = t % 3u; t /= 3u;
  unsigned c = t % 1024u; t /= 1024u;
  unsigned w = t % 14u; unsigned kj = t / 14u;
  unsigned y = h + ki - 1u;
  unsigned xx = w + kj - 1u;
  if (y >= 14u || xx >= 14u) return 0.f;
  return x[(((size_t)b * 1024u + c) * 14u + y) * 14u + xx];
}

// feats[b,n,j<512] = (sum_{u=0..8} F1[9*(512n+j)+u] + F1[...+4]) / 10  -> fp8 A-tiled
// j FASTEST across lanes: a wave's gathers stay in a ~22 KB L1-resident window.
__global__ __launch_bounds__(256) void feat_a_fp8(const float* __restrict__ feat1,
                                                  u8* __restrict__ At) {
  int id = blockIdx.x * 256 + threadIdx.x;
  if (id >= BQ * N1 * 512) return;
  int j = id & 511; int t = id >> 9;
  int n = t % N1; int b = t / N1;
  unsigned L0 = 9u * (unsigned)(512 * n + j);
  float s = 0.f;
#pragma unroll
  for (int u = 0; u < 9; ++u) s += f1val(feat1, b, L0 + u);
  s += f1val(feat1, b, L0 + 4u);
  int p = __builtin_amdgcn_cvt_pk_fp8_f32(s * 0.1f, s * 0.1f, 0, false);
  At[tiled_a_idx(b * N1 + n, j)] = (u8)(p & 0xFF);
}

// H2all[b][n2][i] = (1/18) sum_{u<18} F2[18*(512*n2+i)+u]
__global__ __launch_bounds__(256) void feat_b_stage1(const float* __restrict__ feat2,
                                                     float* __restrict__ H2all) {
  int b = blockIdx.x / M2;
  int n2 = blockIdx.x % M2;
  for (int i = threadIdx.x; i < 512; i += 256) {
    unsigned L0 = 18u * (unsigned)(512 * n2 + i);
    float s = 0.f;
#pragma unroll
    for (int u = 0; u < 18; ++u) s += f2val(feat2, b, L0 + u);
    H2all[((size_t)b * M2 + n2) * 512 + i] = s * (1.0f / 18.0f);
  }
}

// bilinear 14x14 -> 28x28 over the n2 grid, write feats[b,n,512+i] -> fp8 A-tiled
__global__ __launch_bounds__(256) void feat_b_stage2_fp8(const float* __restrict__ H2all,
                                                         u8* __restrict__ At) {
  int id = blockIdx.x * 256 + threadIdx.x;
  if (id >= BQ * 64 * N1) return;
  int n = id % N1; int t = id / N1;
  int ic = t % 64; int b = t / 64;
  int y = n / 28, x = n % 28;
  float sy = 0.5f * (float)y - 0.25f;
  sy = fminf(fmaxf(sy, 0.f), 13.f);
  int y0 = (int)sy, y1 = min(y0 + 1, 13);
  float wy = sy - (float)y0;
  float sx = 0.5f * (float)x - 0.25f;
  sx = fminf(fmaxf(sx, 0.f), 13.f);
  int x0 = (int)sx, x1 = min(x0 + 1, 13);
  float wx = sx - (float)x0;
  float w00 = (1.f - wy) * (1.f - wx), w10 = wy * (1.f - wx);
  float w01 = (1.f - wy) * wx, w11 = wy * wx;
  const float* h00 = H2all + ((size_t)b * M2 + y0 * 14 + x0) * 512 + ic * 8;
  const float* h10 = H2all + ((size_t)b * M2 + y1 * 14 + x0) * 512 + ic * 8;
  const float* h01 = H2all + ((size_t)b * M2 + y0 * 14 + x1) * 512 + ic * 8;
  const float* h11 = H2all + ((size_t)b * M2 + y1 * 14 + x1) * 512 + ic * 8;
  float v[8];
#pragma unroll
  for (int e = 0; e < 8; ++e)
    v[e] = w00 * h00[e] + w10 * h10[e] + w01 * h01[e] + w11 * h11[e];
  int w0 = pack4_fp8(v[0], v[1], v[2], v[3]);
  int w1 = pack4_fp8(v[4], v[5], v[6], v[7]);
  *(int2*)&At[tiled_a_idx(b * N1 + n, 512 + ic * 8)] = make_int2(w0, w1);
}

// memory fp32 -> fp8 B-tiled [tile][kb=32][c=4][row=128][e=8]; rows [MEMN,MEMNP)=0.
__global__ __launch_bounds__(256) void memconv_fp8(const float* __restrict__ mem,
                                                   u8* __restrict__ Bt) {
  int gid = blockIdx.x * 256 + threadIdx.x;
  if (gid >= NTILEB * NKB * 512) return;
  int tile = gid >> 14;            // 32*512 units per tile
  int within = gid & 16383;
  int kb = within >> 9;
  int u = within & 511;
  int c = u >> 7, row = u & 127;
  int n = tile * 128 + row;
  int k0 = kb * 32 + c * 8;
  int w0 = 0, w1 = 0;
  if (n < MEMN) {
    const float* src = mem + (size_t)n * DIMK + k0;
    float4 a = *(const float4*)src;
    float4 b = *(const float4*)(src + 4);
    w0 = pack4_fp8(a.x, a.y, a.z, a.w);
    w1 = pack4_fp8(b.x, b.y, b.z, b.w);
  }
  *(int2*)&Bt[(size_t)gid * 8] = make_int2(w0, w1);
}

// mnorm from fp8 Bt (identical quantized values, 20 MB instead of 80 MB).
__global__ __launch_bounds__(256) void mnorm_fp8(const u8* __restrict__ Bt,
                                                 float* __restrict__ mnorm) {
  __shared__ float part[2][128];
  int tile = blockIdx.x;
  int r = threadIdx.x & 127, hh = threadIdx.x >> 7;
  const u8* base = Bt + (size_t)tile * (NKB * BKB) + r * 8;
  float s = 0.f;
#pragma unroll 4
  for (int ch = hh * 64; ch < hh * 64 + 64; ++ch) {   // chunk = kb*4+c
    int2 d = *(const int2*)(base + (size_t)ch * 1024);
    s += sumsq4_fp8(d.x) + sumsq4_fp8(d.y);
  }
  part[hh][r] = s;
  __syncthreads();
  if (threadIdx.x < 128) {
    int n = tile * 128 + threadIdx.x;
    if (n < MEMN) mnorm[n] = part[0][threadIdx.x] + part[1][threadIdx.x];
  }
}

// ---- fp8 MFMA distance GEMM + row-min (round-17/19 proven: ~183 us, MfmaUtil ~62%) ----
// 128x128 tile, BK=32, 4 waves (2x2). A: global->register direct. B: LDS, 4 slots x
// 4KB staged 3 ahead. vmcnt ledger: per iter issue [A2(k+1), B1(k+3)]; need B(k+1)
// landed before SBAR(k) -> newer = A2(k),B(k+2),A2(k+1),B(k+3) = 6 -> vmcnt(6).
// Tail: k29 vmcnt(5), k30 vmcnt(4). A-reg waits via HW scoreboard.
// NOTE: (256,4) is the occupancy ceiling — unified register demand is ~60 VGPR +
// 64 AGPR (acc) ≈ 124; an 8-wave bound spills the accumulator (round-18: 17x).
// NOTE: 16x16x32 > 32x32x16 here — 16 independent acc updates/K-tile hide MFMA
// latency; the 32x32 shape's 4 chains of 2 stalled the pipe (round-20: 44% util).
__global__ __launch_bounds__(256, 4) void dist_min_mfma(const u8* __restrict__ At,
                                                        const u8* __restrict__ Bt,
                                                        const float* __restrict__ mnorm,
                                                        unsigned int* __restrict__ minu) {
  __shared__ __align__(16) u8 LBs[4][4096];
  const int t = threadIdx.x;
  const int wave = t >> 6, lane = t & 63;

  // bijective XCD chunking (m204): q=961, r=5
  int lid = blockIdx.x;
  const int q = NWG / 8, r = NWG % 8;
  int xcd = lid & 7, pos = lid >> 3;
  int wgid = (xcd < r ? xcd * (q + 1) : r * (q + 1) + (xcd - r) * q) + pos;
  // supertile: 7 row-tiles per group (49 = 7*7), rows fastest within a column
  int g = wgid / (NTILEB * 7), rem = wgid % (NTILEB * 7);
  int bx = rem / 7;            // col tile 0..156
  int by = g * 7 + rem % 7;    // row tile 0..48
  const int row0 = by * 128, col0 = bx * 128;

  f32x4 acc[4][4];
#pragma unroll
  for (int i = 0; i < 4; ++i)
#pragma unroll
    for (int j = 0; j < 4; ++j) acc[i][j] = (f32x4){0.f, 0.f, 0.f, 0.f};

  const int wr = (wave >> 1) * 64, wc = (wave & 1) * 64;
  const int frow = lane & 15, fc = lane >> 4;
  const int half = wave >> 1;
  const int boff = fc * 1024 + (wc + frow) * 8;   // + ni*128 bytes

  // per-lane A base: 32B fragment at ((half*4+fc)*16+frow)*32, +AKB per kb
  const u8* aP = At + (size_t)by * (NKB * AKB) + ((half * 4 + fc) * 16 + frow) * 32;
  const u8* bG = Bt + (size_t)bx * (NKB * BKB) + t * 16;

  ll2 ar0[2], ar1[2];

#define LOAD_A(P, kb)                                        \
  do {                                                       \
    const u8* p_ = aP + (size_t)(kb) * AKB;                  \
    ar##P[0] = *(const ll2*)p_;                              \
    ar##P[1] = *(const ll2*)(p_ + 16);                       \
  } while (0)

#define STAGE_B(S, kb) gload16(bG + (size_t)(kb) * BKB, &LBs[S][wave * 1024])

#define SBAR __builtin_amdgcn_s_barrier()
#define VMW(n) asm volatile("s_waitcnt vmcnt(" #n ")" ::: "memory")

#define COMPUTE(S, P)                                                                        \
  do {                                                                                       \
    i64 b[4];                                                                                \
    _Pragma("unroll") for (int ni = 0; ni < 4; ++ni)                                         \
        b[ni] = *(const i64*)&LBs[S][boff + ni * 128];                                       \
    i64 a0_ = ar##P[0].x, a1_ = ar##P[0].y, a2_ = ar##P[1].x, a3_ = ar##P[1].y;              \
    __builtin_amdgcn_s_setprio(1);                                                           \
    _Pragma("unroll") for (int ni = 0; ni < 4; ++ni) {                                       \
      acc[0][ni] = __builtin_amdgcn_mfma_f32_16x16x32_fp8_fp8(a0_, b[ni], acc[0][ni], 0, 0, 0); \
      acc[1][ni] = __builtin_amdgcn_mfma_f32_16x16x32_fp8_fp8(a1_, b[ni], acc[1][ni], 0, 0, 0); \
      acc[2][ni] = __builtin_amdgcn_mfma_f32_16x16x32_fp8_fp8(a2_, b[ni], acc[2][ni], 0, 0, 0); \
      acc[3][ni] = __builtin_amdgcn_mfma_f32_16x16x32_fp8_fp8(a3_, b[ni], acc[3][ni], 0, 0, 0); \
    }                                                                                        \
    __builtin_amdgcn_s_setprio(0);                                                           \
  } while (0)

  // one K-tile: compute k (slot S, A-parity P), load A(kA), stage B(kS) into (S+3)&3
#define ITER(S, P, PN, kA, kS)       \
  do {                               \
    LOAD_A(PN, kA);                  \
    STAGE_B((S + 3) & 3, kS);        \
    COMPUTE(S, P);                   \
    VMW(6);                          \
    SBAR;                            \
  } while (0)

  // prologue: A(0) -> ar0; B(0..2) -> slots 0..2
  LOAD_A(0, 0);
  STAGE_B(0, 0);
  STAGE_B(1, 1);
  STAGE_B(2, 2);
  VMW(0);
  SBAR;

  // k = 0..27 (stages B(3..30), loads A(1..28))
#pragma unroll 1
  for (int i = 0; i < 7; ++i) {
    int k = i * 4;
    ITER(0, 0, 1, k + 1, k + 3);
    ITER(1, 1, 0, k + 2, k + 4);
    ITER(2, 0, 1, k + 3, k + 5);
    ITER(3, 1, 0, k + 4, k + 6);
  }
  // k=28: load A(29), stage B(31); need B(29): newer = 3+3 = 6
  LOAD_A(1, 29); STAGE_B(3, 31); COMPUTE(0, 0); VMW(6); SBAR;
  // k=29: load A(30); need B(30): newer = A2(29),B(31),A2(30) = 5
  LOAD_A(0, 30); COMPUTE(1, 1); VMW(5); SBAR;
  // k=30: load A(31); need B(31): newer = A2(30),A2(31) = 4
  LOAD_A(1, 31); COMPUTE(2, 0); VMW(4); SBAR;
  // k=31
  COMPUTE(3, 1);
#undef ITER
#undef COMPUTE
#undef LOAD_A
#undef STAGE_B
#undef VMW

  // epilogue: v = mnorm[col] - 2*dot ; row-min across the 16-lane group
  float cmn[4];
#pragma unroll
  for (int ni = 0; ni < 4; ++ni) {
    int gn = col0 + wc + ni * 16 + frow;
    cmn[ni] = (gn < MEMN) ? mnorm[gn] : INFINITY;
  }
#pragma unroll
  for (int mi = 0; mi < 4; ++mi) {
#pragma unroll
    for (int rr = 0; rr < 4; ++rr) {
      float v = INFINITY;
#pragma unroll
      for (int ni = 0; ni < 4; ++ni)
        v = fminf(v, fmaf(-2.f, acc[mi][ni][rr], cmn[ni]));
#pragma unroll
      for (int off = 1; off < 16; off <<= 1)
        v = fminf(v, __shfl_xor(v, off, 64));
      if (frow == 0) {
        int grow = row0 + wr + mi * 16 + fc * 4 + rr;
        atomicMin(&minu[grow], f2ord(v));
      }
    }
  }
}

// ================= epilogue kernels =================

// fused fnorm + scores: 1 wave per row
__global__ __launch_bounds__(256) void scores_fused(const u8* __restrict__ At,
                                                    const unsigned int* __restrict__ minu,
                                                    float* __restrict__ scores) {
  int row = blockIdx.x * 4 + (threadIdx.x >> 6);
  int lane = threadIdx.x & 63;
  float s = 0.f;
#pragma unroll
  for (int qq = 0; qq < 2; ++qq) {
    int2 d = *(const int2*)&At[tiled_a_idx(row, (lane + qq * 64) * 8)];
    s += sumsq4_fp8(d.x);
    s += sumsq4_fp8(d.y);
  }
#pragma unroll
  for (int off = 32; off; off >>= 1) s += __shfl_down(s, off, 64);
  if (lane == 0) scores[row] = sqrtf(fmaxf(s + ord2f(minu[row]), 0.f));
}

__global__ __launch_bounds__(256) void image_max_kernel(const float* __restrict__ scores,
                                                        float* __restrict__ out) {
  __shared__ float red[4];
  const int b = blockIdx.x;
  float m = -INFINITY;
  for (int n = threadIdx.x; n < N1; n += 256) m = fmaxf(m, scores[b * N1 + n]);
#pragma unroll
  for (int off = 32; off; off >>= 1) m = fmaxf(m, __shfl_down(m, off, 64));
  if ((threadIdx.x & 63) == 0) red[threadIdx.x >> 6] = m;
  __syncthreads();
  if (threadIdx.x == 0) out[b] = fmaxf(fmaxf(red[0], red[1]), fmaxf(red[2], red[3]));
}

__global__ __launch_bounds__(256) void upsample_kernel(const float* __restrict__ scores,
                                                       float* __restrict__ out) {
  int o = blockIdx.x * 256 + threadIdx.x;
  if (o >= BQ * OUTHW) return;
  int b = o / OUTHW, rem = o % OUTHW;
  int oy = rem / 224, ox = rem % 224;
  float sy = ((float)oy + 0.5f) * 0.125f - 0.5f;
  sy = fminf(fmaxf(sy, 0.f), 27.f);
  int y0 = (int)sy, y1 = min(y0 + 1, 27);
  float wy = sy - (float)y0;
  float sx = ((float)ox + 0.5f) * 0.125f - 0.5f;
  sx = fminf(fmaxf(sx, 0.f), 27.f);
  int x0 = (int)sx, x1 = min(x0 + 1, 27);
  float wx = sx - (float)x0;
  const float* s = scores + b * N1;
  float v0 = s[y0 * 28 + x0] * (1.f - wy) + s[y1 * 28 + x0] * wy;
  float v1 = s[y0 * 28 + x1] * (1.f - wy) + s[y1 * 28 + x1] * wy;
  out[BQ + o] = v0 * (1.f - wx) + v1 * wx;
}

extern "C" void kernel_launch(void* const* d_in, const int* in_sizes, int n_in,
                              void* d_out, int out_size, void* d_ws, size_t ws_size,
                              hipStream_t stream) {
  const float* feat1 = (const float*)d_in[0];
  const float* feat2 = (const float*)d_in[1];
  const float* memory = (const float*)d_in[2];
  float* out = (float*)d_out;

  char* ws = (char*)d_ws;
  size_t off = 0;
  auto wsalloc = [&](size_t bytes) {
    void* p = ws + off;
    off += (bytes + 255) & ~(size_t)255;
    return p;
  };

  u8* At = (u8*)wsalloc((size_t)NTILEA * NKB * AKB);   // 6.4 MB
  u8* Bt = (u8*)wsalloc((size_t)NTILEB * NKB * BKB);   // 20.6 MB
  float* mnorm = (float*)wsalloc((size_t)MEMN * 4);
  unsigned int* minu = (unsigned int*)wsalloc((size_t)NROWS * 4);
  float* scores = (float*)wsalloc((size_t)NROWS * 4);
  // H2all aliases Bt: stream order guarantees feat_b_stage1/2 finish before memconv
  // overwrites Bt (3.2 MB << Bt's 20.6 MB); mnorm reads Bt after memconv.
  float* H2all = (float*)Bt;

  feat_a_fp8<<<(BQ * N1 * 512) / 256, 256, 0, stream>>>(feat1, At);
  feat_b_stage1<<<BQ * M2, 256, 0, stream>>>(feat2, H2all);
  feat_b_stage2_fp8<<<(BQ * 64 * N1) / 256, 256, 0, stream>>>(H2all, At);
  memconv_fp8<<<(NTILEB * NKB * 512) / 256, 256, 0, stream>>>(memory, Bt);
  mnorm_fp8<<<NTILEB, 256, 0, stream>>>(Bt, mnorm);
  (void)hipMemsetAsync(minu, 0xFF, (size_t)NROWS * 4, stream);

  dist_min_mfma<<<NWG, 256, 0, stream>>>(At, Bt, mnorm, minu);

  scores_fused<<<NROWS / 4, 256, 0, stream>>>(At, minu, scores);
  image_max_kernel<<<BQ, 256, 0, stream>>>(scores, out);
  upsample_kernel<<<(BQ * OUTHW + 255) / 256, 256, 0, stream>>>(scores, out);
}